// Round 4
// baseline (104.546 us; speedup 1.0000x reference)
//
#include <hip/hip_runtime.h>
#include <cstdint>

// 4-layer MLP: [B,64] -> 4 -> 8 -> 8 -> 32, sigmoid each layer. All f32.
// HBM floor: 256 MB read + 128 MB write -> ~61 us @ 6.3 TB/s achievable.
//
// R1 (145us): per-thread row reads -> 8x L1<->L2 amplification, 1 load in flight.
// R2 (184us): VGPR-roundtrip LDS tile + barriers -> staging serialized.
// R3 (95us):  wave-local global_load_lds + vmcnt(0) -> good, but serial
//             issue->stall->compute per tile; ~900cy latency exposed.
// R4: persistent waves, register-pipelined: copy tile to VGPRs, re-issue
//     the NEXT tile's 16 global_load_lds into the same LDS buffer, then
//     compute from registers -> load latency fully hidden under compute.
//     Weights read via uniform (scalar-cache) loads; no LDS staging, no
//     __syncthreads anywhere. 64 KB LDS/block -> 2 blocks/CU.

#define IN_DIM 64
#define OUT_DIM 32
#define THREADS 256
#define WAVES_PER_BLOCK 4
#define ROWS_PER_WAVE 64
#define GRID_BLOCKS 512

__device__ __forceinline__ float fast_sigmoid(float z) {
    float e = __expf(-z);
    return __builtin_amdgcn_rcpf(1.0f + e);
}

__global__ __launch_bounds__(THREADS) void mlp4_kernel(
    const float* __restrict__ x,
    const float* __restrict__ W0, const float* __restrict__ b0,
    const float* __restrict__ W1, const float* __restrict__ b1,
    const float* __restrict__ W2, const float* __restrict__ b2,
    const float* __restrict__ W3, const float* __restrict__ b3,
    float* __restrict__ out, int batch)
{
    // One 16 KB buffer per wave (64 rows x 16 float4), 4 waves = 64 KB.
    __shared__ float4 sx[WAVES_PER_BLOCK * 1024];

    const int tid  = threadIdx.x;
    const int wave = tid >> 6;
    const int lane = tid & 63;

    const long long gw        = (long long)blockIdx.x * WAVES_PER_BLOCK + wave;
    const long long rowStride = (long long)GRID_BLOCKS * WAVES_PER_BLOCK * ROWS_PER_WAVE;
    const long long row0      = gw * ROWS_PER_WAVE;
    if (row0 >= batch) return;   // wave-uniform

    const float4* xg    = reinterpret_cast<const float4*>(x);
    const int     wbase = wave << 10;   // this wave's float4 base in sx

    // Issue 16x global_load_lds (1 KB each) for the 64-row tile at rowT.
    // LDS dest is linear (HW: wave-uniform base + lane*16); bank-conflict-free
    // readback via XOR-pre-swizzled GLOBAL source: slot p=(r<<4)|c' holds
    // chunk c'^(r&15) of row r -- a permutation within one contiguous 256 B
    // row, so coalescing is preserved.
    auto issue = [&](long long rowT) {
        #pragma unroll
        for (int k = 0; k < 16; ++k) {
            const int p = (k << 6) | lane;
            const int r = p >> 4;
            const int c = (p & 15) ^ (r & 15);
            long long row = rowT + r;
            if (row >= batch) row = batch - 1;   // clamp (batch%64==0 anyway)
            __builtin_amdgcn_global_load_lds(
                reinterpret_cast<const uint32_t*>(xg + row * 16 + c),
                reinterpret_cast<uint32_t*>(&sx[wbase + (k << 6)]),
                16, 0, 0);
        }
    };

    issue(row0);   // prologue: fill the pipeline

    for (long long r0 = row0; r0 < batch; r0 += rowStride) {
        // Wait for this tile's staging to land in LDS.
        asm volatile("s_waitcnt vmcnt(0)" ::: "memory");
        __builtin_amdgcn_sched_barrier(0);

        // Copy my row LDS -> registers (swizzled slots; balanced banks).
        const int myBase = wbase | (lane << 4);
        const int rx     = lane & 15;
        float4 xr[16];
        #pragma unroll
        for (int c = 0; c < 16; ++c)
            xr[c] = sx[myBase | (c ^ rx)];
        asm volatile("s_waitcnt lgkmcnt(0)" ::: "memory");
        __builtin_amdgcn_sched_barrier(0);

        // Prefetch the NEXT tile into the same buffer; its LDS writes land
        // while we compute from registers below.
        const long long rn = r0 + rowStride;
        if (rn < batch) issue(rn);

        // ---- Layer 0: 64 -> 4 (weights via uniform scalar-cache loads) ----
        float acc[4] = {b0[0], b0[1], b0[2], b0[3]};
        #pragma unroll
        for (int c = 0; c < 16; ++c) {
            const float4 xv = xr[c];
            #pragma unroll
            for (int o = 0; o < 4; ++o) {
                const float4 wv = *reinterpret_cast<const float4*>(&W0[o * 64 + 4 * c]);
                acc[o] = fmaf(xv.x, wv.x, acc[o]);
                acc[o] = fmaf(xv.y, wv.y, acc[o]);
                acc[o] = fmaf(xv.z, wv.z, acc[o]);
                acc[o] = fmaf(xv.w, wv.w, acc[o]);
            }
        }
        float h0[4];
        #pragma unroll
        for (int o = 0; o < 4; ++o) h0[o] = fast_sigmoid(acc[o]);

        // ---- Layer 1: 4 -> 8 ----
        float h1[8];
        #pragma unroll
        for (int j = 0; j < 8; ++j) {
            float a = b1[j];
            #pragma unroll
            for (int c = 0; c < 4; ++c) a = fmaf(h0[c], W1[j * 4 + c], a);
            h1[j] = fast_sigmoid(a);
        }

        // ---- Layer 2: 8 -> 8 ----
        float h2[8];
        #pragma unroll
        for (int j = 0; j < 8; ++j) {
            float a = b2[j];
            #pragma unroll
            for (int i = 0; i < 8; ++i) a = fmaf(h1[i], W2[j * 8 + i], a);
            h2[j] = fast_sigmoid(a);
        }

        // ---- Layer 3: 8 -> 32, store 8x float4 ----
        const long long row = r0 + lane;
        if (row < batch) {
            float4* op = reinterpret_cast<float4*>(out + (size_t)row * OUT_DIM);
            #pragma unroll
            for (int q = 0; q < OUT_DIM / 4; ++q) {
                float o4[4];
                #pragma unroll
                for (int r2 = 0; r2 < 4; ++r2) {
                    const int oidx = q * 4 + r2;
                    float a = b3[oidx];
                    #pragma unroll
                    for (int j = 0; j < 8; ++j)
                        a = fmaf(h2[j], W3[oidx * 8 + j], a);
                    o4[r2] = fast_sigmoid(a);
                }
                op[q] = make_float4(o4[0], o4[1], o4[2], o4[3]);
            }
        }
    }
}

extern "C" void kernel_launch(void* const* d_in, const int* in_sizes, int n_in,
                              void* d_out, int out_size, void* d_ws, size_t ws_size,
                              hipStream_t stream) {
    const float* x  = (const float*)d_in[0];
    const float* W0 = (const float*)d_in[1];
    const float* b0 = (const float*)d_in[2];
    const float* W1 = (const float*)d_in[3];
    const float* b1 = (const float*)d_in[4];
    const float* W2 = (const float*)d_in[5];
    const float* b2 = (const float*)d_in[6];
    const float* W3 = (const float*)d_in[7];
    const float* b3 = (const float*)d_in[8];
    float* out = (float*)d_out;

    const int batch = in_sizes[0] / IN_DIM;  // 1,000,000

    mlp4_kernel<<<GRID_BLOCKS, THREADS, 0, stream>>>(x, W0, b0, W1, b1,
                                                     W2, b2, W3, b3, out, batch);
}